// Round 5
// baseline (604.631 us; speedup 1.0000x reference)
//
#include <hip/hip_runtime.h>

#define BB 8
#define NN 1024
#define CC 768
#define OO 768
#define RR 16
#define MM (BB*NN)      /* 8192  */
#define KK (CC*RR)      /* 12288 */
#define BM 64
#define BO 128
#define CB32 24         /* 32-wide c-blocks */
#define MTILES (MM/BM)  /* 128 */
#define OTILES (OO/BO)  /* 6   */
#define NBLK (MTILES*OTILES) /* 768 = exactly 3 blocks/CU */
#define NTHR 256        /* 4 waves: 1(m) x 4(o); wave tile 64m x 32o */

typedef __bf16 bf16x8 __attribute__((ext_vector_type(8)));
typedef float  f32x4  __attribute__((ext_vector_type(4)));
typedef float  f32x2  __attribute__((ext_vector_type(2)));

__device__ static __forceinline__ f32x2 mk2(float a, float b) {
    f32x2 v; v[0] = a; v[1] = b; return v;
}

// ---- prep: weight fp32 -> bf16, layout wbf[o][cb32][r][32c]:
//      index = o*KK + (c>>5)*512 + r*32 + (c&31);  a 64-k MFMA tile = (r=2u,2u+1) x 32 c,
//      so every k-tile of a cb32 block shares one base pointer + <=1KB immediates.
//      Also bias_term[n,o] = coef[n,:]·bias[o,:] ----
__global__ __launch_bounds__(256) void k_prep(const float* __restrict__ w,
                                              const float* __restrict__ coef,
                                              const float* __restrict__ bias,
                                              __bf16* __restrict__ wbf,
                                              float* __restrict__ bterm) {
    long id = blockIdx.x;
    if (id < 4608) {                       // 1,179,648 threads: (o, r, cb8-of-8c) each
        int e  = (int)id * 256 + threadIdx.x;
        int cb8 = e % 96;                  // c-block of 8
        int t2  = e / 96;
        int r   = t2 & 15;
        int o   = t2 >> 4;
        const float* wp = w + ((long)o * CC + cb8 * 8) * RR + r;   // stride-RR gather
        bf16x8 v;
#pragma unroll
        for (int j = 0; j < 8; ++j) v[j] = (__bf16)wp[j * RR];
        *(bf16x8*)(wbf + (long)o * KK + (cb8 >> 2) * 512 + r * 32 + (cb8 & 3) * 8) = v;
    } else {                               // bias_term: 1024*768 dots of length 16
        int i = (int)(id - 4608) * 256 + threadIdx.x;
        int n = i / OO, o = i - n * OO;
        float4 c0 = *(const float4*)(coef + n * RR);
        float4 c1 = *(const float4*)(coef + n * RR + 4);
        float4 c2 = *(const float4*)(coef + n * RR + 8);
        float4 c3 = *(const float4*)(coef + n * RR + 12);
        float4 b0 = *(const float4*)(bias + o * RR);
        float4 b1 = *(const float4*)(bias + o * RR + 4);
        float4 b2 = *(const float4*)(bias + o * RR + 8);
        float4 b3 = *(const float4*)(bias + o * RR + 12);
        float s = c0.x*b0.x + c0.y*b0.y + c0.z*b0.z + c0.w*b0.w
                + c1.x*b1.x + c1.y*b1.y + c1.z*b1.z + c1.w*b1.w
                + c2.x*b2.x + c2.y*b2.y + c2.z*b2.z + c2.w*b2.w
                + c3.x*b3.x + c3.y*b3.y + c3.z*b3.z + c3.w*b3.w;
        bterm[i] = s;
    }
}

// ---- main GEMM: NO LDS, NO BARRIERS.
// out[m,o] = sum_{r,c} (coef[n,r]*x[m,c]) * W[o,c,r] + bterm[n,o]
// A-frag (16x16x32: row=lane&15, k_local=quad*8+j) = coef[n, 2u+ks] * x[row][cb32*32+quad*8+j]
//   -> synthesized in registers; the lane's 8 x-values serve BOTH k-steps and are
//      register-resident for 8 consecutive k-tiles (all r of the c-block).
// B-frag read directly from global: the 16KB per-ktile W-window is shared by all waves
// reading it and the 3MB o-panel is L2-resident (stage only what doesn't cache-fit).
// Waves are fully independent -> the barrier-drain stall of all LDS variants is gone.
__global__ __launch_bounds__(NTHR, 3) void k_gemm(const float* __restrict__ x,
                                                  const float* __restrict__ coef,
                                                  const __bf16* __restrict__ wbf,
                                                  const float* __restrict__ bterm,
                                                  float* __restrict__ out) {
    const int tid = threadIdx.x;

    // XCD swizzle: consecutive blocks on one XCD -> each XCD spans <=2 o-panels,
    // per-ktile W-window shared through L2. 768 % 8 == 0 -> bijective.
    int bid = blockIdx.x;
    int swz = (bid & 7) * (NBLK / 8) + (bid >> 3);
    const int otile = swz >> 7;      // 0..5
    const int mtile = swz & 127;     // 0..127
    const int m0 = mtile * BM, o0 = otile * BO;

    const int lane = tid & 63, wc = tid >> 6;       // 4 o-waves
    const int lrow = lane & 15, quad = lane >> 4;

    // ---- per-lane bases: 4 m-row-blocks (im), 2 B o-rows (io) ----
    const float* xb[4];
    const float* cfb[4];
#pragma unroll
    for (int im = 0; im < 4; ++im) {
        int mg = m0 + im * 16 + lrow;
        int n  = mg & (NN - 1);
        xb[im]  = x + (long)mg * CC;
        cfb[im] = coef + n * RR;
    }
    const __bf16* wb0 = wbf + (long)(o0 + wc * 32 + lrow) * KK;        // io=0
    const __bf16* wb1 = wbf + (long)(o0 + wc * 32 + 16 + lrow) * KK;   // io=1

    f32x4 acc[4][2] = {};

#pragma unroll 1
    for (int cb = 0; cb < CB32; ++cb) {
        // lane's x window: 8 floats per row, reused for all 16 r (8 k-tiles)
        f32x2 xw[4][4];
#pragma unroll
        for (int im = 0; im < 4; ++im) {
            float4 a = *(const float4*)(xb[im] + cb * 32 + quad * 8);
            float4 b = *(const float4*)(xb[im] + cb * 32 + quad * 8 + 4);
            xw[im][0] = mk2(a.x, a.y); xw[im][1] = mk2(a.z, a.w);
            xw[im][2] = mk2(b.x, b.y); xw[im][3] = mk2(b.z, b.w);
        }
#pragma unroll
        for (int u = 0; u < 8; ++u) {      // k-tile = (r=2u, 2u+1) x 32 c
            // B fragments straight from global (L1/L2-hot window)
            bf16x8 bfr[2][2];              // [ks][io]
#pragma unroll
            for (int ks = 0; ks < 2; ++ks) {
                int eoff = u * 64 + ks * 32 + quad * 8;   // elements; +cb base below
                bfr[ks][0] = *(const bf16x8*)(wb0 + eoff);
                bfr[ks][1] = *(const bf16x8*)(wb1 + eoff);
            }
            // coef pairs for r = 2u, 2u+1 (one dwordx2 per row, L1-broadcast)
            f32x2 cf2[4];
#pragma unroll
            for (int im = 0; im < 4; ++im) cf2[im] = *(const f32x2*)(cfb[im] + 2 * u);
#pragma unroll
            for (int ks = 0; ks < 2; ++ks) {
#pragma unroll
                for (int im = 0; im < 4; ++im) {
                    const float cs = ks ? cf2[im][1] : cf2[im][0];
                    const f32x2 c2 = mk2(cs, cs);
                    bf16x8 af;
#pragma unroll
                    for (int h = 0; h < 4; ++h) {
                        f32x2 pr = xw[im][h] * c2;        // v_pk_mul_f32
                        af[2 * h]     = (__bf16)pr[0];
                        af[2 * h + 1] = (__bf16)pr[1];
                    }
                    acc[im][0] = __builtin_amdgcn_mfma_f32_16x16x32_bf16(
                        af, bfr[ks][0], acc[im][0], 0, 0, 0);
                    acc[im][1] = __builtin_amdgcn_mfma_f32_16x16x32_bf16(
                        af, bfr[ks][1], acc[im][1], 0, 0, 0);
                }
            }
        }
        wb0 += 512; wb1 += 512;            // advance one cb32 block (16 r x 32 c)
    }

    // ---- epilogue: D col=lane&15 (o), row=quad*4+reg (m); add bias_term ----
#pragma unroll
    for (int im = 0; im < 4; ++im) {
#pragma unroll
        for (int io = 0; io < 2; ++io) {
            int o = o0 + wc * 32 + io * 16 + lrow;
#pragma unroll
            for (int r = 0; r < 4; ++r) {
                int moff = im * 16 + quad * 4 + r;
                long m = m0 + moff;
                int n = (int)(m & (NN - 1));
                out[m * OO + o] = acc[im][io][r] + bterm[(long)n * OO + o];
            }
        }
    }
}

// ---- fallback if workspace too small (correctness-only) ----
__global__ void k_naive(const float* __restrict__ x, const float* __restrict__ coef,
                        const float* __restrict__ w, const float* __restrict__ bias,
                        float* __restrict__ out) {
    long i = (long)blockIdx.x * 256 + threadIdx.x;
    if (i >= (long)MM * OO) return;
    int o = (int)(i % OO);
    long m = i / OO;
    int n = (int)(m & (NN - 1));
    float cf[16];
#pragma unroll
    for (int r = 0; r < 16; ++r) cf[r] = coef[n * RR + r];
    const float* xr = x + m * CC;
    const float* wr = w + (long)o * CC * RR;
    float s = 0.f;
    for (int c = 0; c < CC; ++c) {
        float t = 0.f;
#pragma unroll
        for (int r = 0; r < 16; ++r) t += cf[r] * wr[c * RR + r];
        s += xr[c] * t;
    }
    float bs = 0.f;
#pragma unroll
    for (int r = 0; r < 16; ++r) bs += cf[r] * bias[o * RR + r];
    out[i] = s + bs;
}

extern "C" void kernel_launch(void* const* d_in, const int* in_sizes, int n_in,
                              void* d_out, int out_size, void* d_ws, size_t ws_size,
                              hipStream_t stream) {
    const float* x    = (const float*)d_in[0];
    const float* coef = (const float*)d_in[1];
    const float* w    = (const float*)d_in[2];
    const float* bias = (const float*)d_in[3];
    float* out = (float*)d_out;

    const size_t wbf_bytes = (size_t)OO * KK * sizeof(__bf16);   // 18,874,368
    const size_t bt_bytes  = (size_t)NN * OO * sizeof(float);    //  3,145,728

    if (ws_size >= wbf_bytes + bt_bytes) {
        __bf16* wbf  = (__bf16*)d_ws;
        float*  btrm = (float*)((char*)d_ws + wbf_bytes);
        k_prep<<<7680, 256, 0, stream>>>(w, coef, bias, wbf, btrm);
        k_gemm<<<NBLK, NTHR, 0, stream>>>(x, coef, wbf, btrm, out);
    } else {
        k_naive<<<(int)(((long)MM * OO + 255) / 256), 256, 0, stream>>>(x, coef, w, bias, out);
    }
}

// Round 6
// 462.944 us; speedup vs baseline: 1.3061x; 1.3061x over previous
//
#include <hip/hip_runtime.h>

#define BB 8
#define NN 1024
#define CC 768
#define OO 768
#define RR 16
#define MM (BB*NN)      /* 8192  */
#define KK (CC*RR)      /* 12288 */
#define BM 64
#define BO 128
#define BK 64
#define CW 12           /* 64-wide c-windows */
#define MTILES (MM/BM)  /* 128 */
#define OTILES (OO/BO)  /* 6   */
#define NBLK (MTILES*OTILES) /* 768 = exactly 3 blocks/CU */
#define NTHR 256        /* 4 o-waves; wave tile 64m x 32o */

typedef __bf16 bf16x8 __attribute__((ext_vector_type(8)));
typedef float  f32x4  __attribute__((ext_vector_type(4)));
typedef float  f32x2  __attribute__((ext_vector_type(2)));

__device__ static __forceinline__ void gl_lds16(const void* g, void* l) {
    __builtin_amdgcn_global_load_lds(
        (const __attribute__((address_space(1))) void*)g,
        (__attribute__((address_space(3))) void*)l,
        16, 0, 0);
}

__device__ static __forceinline__ f32x2 mk2(float a, float b) {
    f32x2 v; v[0] = a; v[1] = b; return v;
}

// ---- prep: weight fp32 -> bf16 in R-MAJOR-K layout wbf[o][r*768+c] = w[o][c][r],
//      coalesced reads: 16-lane groups (r=0..15) read 16 consecutive floats per line.
//      Also bias_term[n,o] = coef[n,:]·bias[o,:] ----
__global__ __launch_bounds__(256) void k_prep(const float* __restrict__ w,
                                              const float* __restrict__ coef,
                                              const float* __restrict__ bias,
                                              __bf16* __restrict__ wbf,
                                              float* __restrict__ bterm) {
    long id = blockIdx.x;
    if (id < 4608) {                       // (o, cb8) x 16 r-lanes
        int r = threadIdx.x & 15, g = threadIdx.x >> 4;
        long f = id * 16 + g;              // 0..73727 = 96*768-1
        int cb8 = (int)(f % 96);           // c-block of 8
        int o   = (int)(f / 96);
        const float* wp = w + ((long)o * CC + cb8 * 8) * RR + r;
        bf16x8 v;                          // lanes r=0..15 cover one 64B line per j
#pragma unroll
        for (int j = 0; j < 8; ++j) v[j] = (__bf16)wp[j * RR];
        *(bf16x8*)(wbf + (long)o * KK + r * CC + cb8 * 8) = v;
    } else {                               // bias_term: 1024*768 dots of length 16
        int i = (int)(id - 4608) * 256 + threadIdx.x;
        int n = i / OO, o = i - n * OO;
        float4 c0 = *(const float4*)(coef + n * RR);
        float4 c1 = *(const float4*)(coef + n * RR + 4);
        float4 c2 = *(const float4*)(coef + n * RR + 8);
        float4 c3 = *(const float4*)(coef + n * RR + 12);
        float4 b0 = *(const float4*)(bias + o * RR);
        float4 b1 = *(const float4*)(bias + o * RR + 4);
        float4 b2 = *(const float4*)(bias + o * RR + 8);
        float4 b3 = *(const float4*)(bias + o * RR + 12);
        float s = c0.x*b0.x + c0.y*b0.y + c0.z*b0.z + c0.w*b0.w
                + c1.x*b1.x + c1.y*b1.y + c1.z*b1.z + c1.w*b1.w
                + c2.x*b2.x + c2.y*b2.y + c2.z*b2.z + c2.w*b2.w
                + c3.x*b3.x + c3.y*b3.y + c3.z*b3.z + c3.w*b3.w;
        bterm[i] = s;
    }
}

// ---- main GEMM (reg-A + LDS-B, round-1 skeleton):
// out[m,o] = sum_{r,c} (coef[n,r]*x[m,c]) * W[o,c,r] + bterm[n,o],  k = r*768 + c.
// k-tile (cw,r): 64 consecutive c at fixed r. A-frag (row=lane&15, k_local=quad*8+j):
//   A = coef[n,r] * x[row][cw*64 + ks*32 + quad*8 + j]
// -> A synthesized in registers; lane's 16 x-values live in regs for 16 k-tiles (all r).
// LDS holds only B (16KB tile, double-buffered, XOR-swizzled as in the verified 218us rev).
// One barrier per k-tile; 3 blocks/CU cover the drain. LDS/CU/ktile: 240KB -> 96KB.
__global__ __launch_bounds__(NTHR, 3) void k_gemm(const float* __restrict__ x,
                                                  const float* __restrict__ coef,
                                                  const __bf16* __restrict__ wbf,
                                                  const float* __restrict__ bterm,
                                                  float* __restrict__ out) {
    __shared__ __bf16 lB[2][BO * BK];   // 2 x 16 KB

    const int tid = threadIdx.x;

    int bid = blockIdx.x;
    int swz = (bid & 7) * (NBLK / 8) + (bid >> 3);   // 768%8==0 -> bijective
    const int otile = swz >> 7;      // 0..5
    const int mtile = swz & 127;     // 0..127
    const int m0 = mtile * BM, o0 = otile * BO;

    const int lane = tid & 63, wc = tid >> 6;       // 4 o-waves
    const int lrow = lane & 15, quad = lane >> 4;
    const int nbase = m0 & (NN - 1);

    // per-row-block bases: x rows (4 ptrs), coef via one ptr + imm offsets
    const float* xb[4];
#pragma unroll
    for (int im = 0; im < 4; ++im) xb[im] = x + (long)(m0 + im * 16 + lrow) * CC;
    const float* cptr = coef + (long)(nbase + lrow) * RR;   // + im*256 + r floats

    f32x4 acc[4][2] = {};

    // stage B-tile at k-offset koff into buffer b (async DMA, global-side XOR swizzle)
    auto STAGE = [&](int b, int koff) {
#pragma unroll
        for (int s = 0; s < 4; ++s) {
            int u = s * 256 + tid;             // 1024 chunks of 16B
            int row = u >> 3, cl = u & 7;
            int g = cl ^ (row & 7);
            const __bf16* gp = wbf + (long)(o0 + row) * KK + koff + g * 8;
            gl_lds16(gp, ((char*)lB[b]) + u * 16);
        }
    };

    STAGE(0, 0);                                   // tile (cw=0, r=0)
    f32x2 xw[4][8];                                // lane's 16 x per row-block
#pragma unroll
    for (int im = 0; im < 4; ++im) {
        float4 a  = *(const float4*)(xb[im] + quad * 8);
        float4 b4 = *(const float4*)(xb[im] + quad * 8 + 4);
        float4 c4 = *(const float4*)(xb[im] + 32 + quad * 8);
        float4 d4 = *(const float4*)(xb[im] + 32 + quad * 8 + 4);
        xw[im][0] = mk2(a.x, a.y);  xw[im][1] = mk2(a.z, a.w);
        xw[im][2] = mk2(b4.x, b4.y); xw[im][3] = mk2(b4.z, b4.w);
        xw[im][4] = mk2(c4.x, c4.y); xw[im][5] = mk2(c4.z, c4.w);
        xw[im][6] = mk2(d4.x, d4.y); xw[im][7] = mk2(d4.z, d4.w);
    }
    __syncthreads();

#pragma unroll 1
    for (int cw = 0; cw < CW; ++cw) {
        if (cw) {                                  // refresh x window (16 loads / 16 tiles)
#pragma unroll
            for (int im = 0; im < 4; ++im) {
                float4 a  = *(const float4*)(xb[im] + cw * 64 + quad * 8);
                float4 b4 = *(const float4*)(xb[im] + cw * 64 + quad * 8 + 4);
                float4 c4 = *(const float4*)(xb[im] + cw * 64 + 32 + quad * 8);
                float4 d4 = *(const float4*)(xb[im] + cw * 64 + 32 + quad * 8 + 4);
                xw[im][0] = mk2(a.x, a.y);  xw[im][1] = mk2(a.z, a.w);
                xw[im][2] = mk2(b4.x, b4.y); xw[im][3] = mk2(b4.z, b4.w);
                xw[im][4] = mk2(c4.x, c4.y); xw[im][5] = mk2(c4.z, c4.w);
                xw[im][6] = mk2(d4.x, d4.y); xw[im][7] = mk2(d4.z, d4.w);
            }
        }
#pragma unroll
        for (int r = 0; r < RR; ++r) {             // fully unrolled: static reg indices
            const int cur = r & 1;
            if (!(cw == CW - 1 && r == RR - 1)) {
                int koff = (r < RR - 1) ? ((r + 1) * CC + cw * 64) : ((cw + 1) * 64);
                STAGE(cur ^ 1, koff);              // drains at end-of-tile barrier
            }
            float cf[4];
#pragma unroll
            for (int im = 0; im < 4; ++im) cf[im] = cptr[im * 256 + r];  // imm offsets, L1
#pragma unroll
            for (int ks = 0; ks < 2; ++ks) {
                const int kb = ks * 4 + quad;
                bf16x8 bfr[2];
#pragma unroll
                for (int io = 0; io < 2; ++io) {
                    int brow = wc * 32 + io * 16 + lrow;
                    bfr[io] = *(const bf16x8*)(&lB[cur][brow * BK + ((kb ^ (brow & 7))) * 8]);
                }
#pragma unroll
                for (int im = 0; im < 4; ++im) {
                    const f32x2 c2 = mk2(cf[im], cf[im]);
                    bf16x8 af;
#pragma unroll
                    for (int h = 0; h < 4; ++h) {
                        f32x2 pr = xw[im][ks * 4 + h] * c2;   // v_pk_mul_f32
                        af[2 * h]     = (__bf16)pr[0];
                        af[2 * h + 1] = (__bf16)pr[1];
                    }
                    acc[im][0] = __builtin_amdgcn_mfma_f32_16x16x32_bf16(
                        af, bfr[0], acc[im][0], 0, 0, 0);
                    acc[im][1] = __builtin_amdgcn_mfma_f32_16x16x32_bf16(
                        af, bfr[1], acc[im][1], 0, 0, 0);
                }
            }
            __syncthreads();   // single barrier/k-tile: drains DMA, guards buffers
        }
    }

    // ---- epilogue: D col=lane&15 (o), row=quad*4+reg (m); add bias_term ----
#pragma unroll
    for (int im = 0; im < 4; ++im) {
#pragma unroll
        for (int io = 0; io < 2; ++io) {
            int o = o0 + wc * 32 + io * 16 + lrow;
#pragma unroll
            for (int rr2 = 0; rr2 < 4; ++rr2) {
                int moff = im * 16 + quad * 4 + rr2;
                long m = m0 + moff;
                out[m * OO + o] = acc[im][io][rr2] + bterm[(long)(nbase + moff) * OO + o];
            }
        }
    }
}

// ---- fallback if workspace too small (correctness-only) ----
__global__ void k_naive(const float* __restrict__ x, const float* __restrict__ coef,
                        const float* __restrict__ w, const float* __restrict__ bias,
                        float* __restrict__ out) {
    long i = (long)blockIdx.x * 256 + threadIdx.x;
    if (i >= (long)MM * OO) return;
    int o = (int)(i % OO);
    long m = i / OO;
    int n = (int)(m & (NN - 1));
    float cf[16];
#pragma unroll
    for (int r = 0; r < 16; ++r) cf[r] = coef[n * RR + r];
    const float* xr = x + m * CC;
    const float* wr = w + (long)o * CC * RR;
    float s = 0.f;
    for (int c = 0; c < CC; ++c) {
        float t = 0.f;
#pragma unroll
        for (int r = 0; r < 16; ++r) t += cf[r] * wr[c * RR + r];
        s += xr[c] * t;
    }
    float bs = 0.f;
#pragma unroll
    for (int r = 0; r < 16; ++r) bs += cf[r] * bias[o * RR + r];
    out[i] = s + bs;
}

extern "C" void kernel_launch(void* const* d_in, const int* in_sizes, int n_in,
                              void* d_out, int out_size, void* d_ws, size_t ws_size,
                              hipStream_t stream) {
    const float* x    = (const float*)d_in[0];
    const float* coef = (const float*)d_in[1];
    const float* w    = (const float*)d_in[2];
    const float* bias = (const float*)d_in[3];
    float* out = (float*)d_out;

    const size_t wbf_bytes = (size_t)OO * KK * sizeof(__bf16);   // 18,874,368
    const size_t bt_bytes  = (size_t)NN * OO * sizeof(float);    //  3,145,728

    if (ws_size >= wbf_bytes + bt_bytes) {
        __bf16* wbf  = (__bf16*)d_ws;
        float*  btrm = (float*)((char*)d_ws + wbf_bytes);
        k_prep<<<7680, 256, 0, stream>>>(w, coef, bias, wbf, btrm);
        k_gemm<<<NBLK, NTHR, 0, stream>>>(x, coef, wbf, btrm, out);
    } else {
        k_naive<<<(int)(((long)MM * OO + 255) / 256), 256, 0, stream>>>(x, coef, w, bias, out);
    }
}

// Round 7
// 455.085 us; speedup vs baseline: 1.3286x; 1.0173x over previous
//
#include <hip/hip_runtime.h>

#define BB 8
#define NN 1024
#define CC 768
#define OO 768
#define RR 16
#define MM (BB*NN)      /* 8192  */
#define KK (CC*RR)      /* 12288 */
#define BM 64
#define BO 128
#define BK 64
#define CW 12           /* 64-wide c-windows */
#define MTILES (MM/BM)  /* 128 */
#define OTILES (OO/BO)  /* 6   */
#define NBLK (MTILES*OTILES) /* 768 = exactly 3 blocks/CU */
#define NTHR 256        /* 4 o-waves; wave tile 64m x 32o */

typedef __bf16 bf16x8 __attribute__((ext_vector_type(8)));
typedef float  f32x4  __attribute__((ext_vector_type(4)));
typedef float  f32x2  __attribute__((ext_vector_type(2)));

__device__ static __forceinline__ void gl_lds16(const void* g, void* l) {
    __builtin_amdgcn_global_load_lds(
        (const __attribute__((address_space(1))) void*)g,
        (__attribute__((address_space(3))) void*)l,
        16, 0, 0);
}

__device__ static __forceinline__ f32x2 mk2(float a, float b) {
    f32x2 v; v[0] = a; v[1] = b; return v;
}

// ---- prep: weight fp32 -> bf16, BLOCKED-SEQUENTIAL layout:
//      wbf[o][cw][r][c64]: index = o*KK + (c>>6)*1024 + r*64 + (c&63) = w[o][c][r].
//      The GEMM walks (cw outer, r inner) -> koff advances +64 elems (128B) per
//      k-tile MONOTONICALLY: same prefetch-friendly stream shape as the 96MB-FETCH
//      round-1 walk. (r-major non-blocked layout thrashed L2: 673MB FETCH.)
//      Also bias_term[n,o] = coef[n,:]·bias[o,:] ----
__global__ __launch_bounds__(256) void k_prep(const float* __restrict__ w,
                                              const float* __restrict__ coef,
                                              const float* __restrict__ bias,
                                              __bf16* __restrict__ wbf,
                                              float* __restrict__ bterm) {
    long id = blockIdx.x;
    if (id < 4608) {                       // (o, cb8) x 16 r-lanes, coalesced reads
        int r = threadIdx.x & 15, g = threadIdx.x >> 4;
        long f = id * 16 + g;              // 0..73727 = 768*96-1
        int cb8 = (int)(f % 96);           // c-block of 8
        int o   = (int)(f / 96);
        const float* wp = w + ((long)o * CC + cb8 * 8) * RR + r;
        bf16x8 v;                          // lanes r=0..15 cover one 64B line per j
#pragma unroll
        for (int j = 0; j < 8; ++j) v[j] = (__bf16)wp[j * RR];
        // c = cb8*8..cb8*8+7 all in one 64-c block: contiguous 16B store
        *(bf16x8*)(wbf + (long)o * KK + (cb8 >> 3) * 1024 + r * 64 + (cb8 & 7) * 8) = v;
    } else {                               // bias_term: 1024*768 dots of length 16
        int i = (int)(id - 4608) * 256 + threadIdx.x;
        int n = i / OO, o = i - n * OO;
        float4 c0 = *(const float4*)(coef + n * RR);
        float4 c1 = *(const float4*)(coef + n * RR + 4);
        float4 c2 = *(const float4*)(coef + n * RR + 8);
        float4 c3 = *(const float4*)(coef + n * RR + 12);
        float4 b0 = *(const float4*)(bias + o * RR);
        float4 b1 = *(const float4*)(bias + o * RR + 4);
        float4 b2 = *(const float4*)(bias + o * RR + 8);
        float4 b3 = *(const float4*)(bias + o * RR + 12);
        float s = c0.x*b0.x + c0.y*b0.y + c0.z*b0.z + c0.w*b0.w
                + c1.x*b1.x + c1.y*b1.y + c1.z*b1.z + c1.w*b1.w
                + c2.x*b2.x + c2.y*b2.y + c2.z*b2.z + c2.w*b2.w
                + c3.x*b3.x + c3.y*b3.y + c3.z*b3.z + c3.w*b3.w;
        bterm[i] = s;
    }
}

// ---- main GEMM (reg-A + LDS-B, sequential B-walk):
// out[m,o] = sum_{r,c} (coef[n,r]*x[m,c]) * W[o,c,r] + bterm[n,o]
// k-tile (cw,r): 64 consecutive c at fixed r. A-frag (row=lane&15, k_local=quad*8+j):
//   A = coef[n,r] * x[row][cw*64 + ks*32 + quad*8 + j]
// -> A synthesized in registers; lane's 16 x-values live in regs for 16 k-tiles (all r).
// B-frag from wbf[o][cw][r][c64]: koff = cw*1024 + r*64, strictly monotonic.
// LDS holds only B (16KB tile, double-buffered, XOR-swizzled); one barrier per k-tile;
// 3 blocks/CU cover the drain.
__global__ __launch_bounds__(NTHR, 3) void k_gemm(const float* __restrict__ x,
                                                  const float* __restrict__ coef,
                                                  const __bf16* __restrict__ wbf,
                                                  const float* __restrict__ bterm,
                                                  float* __restrict__ out) {
    __shared__ __bf16 lB[2][BO * BK];   // 2 x 16 KB

    const int tid = threadIdx.x;

    int bid = blockIdx.x;
    int swz = (bid & 7) * (NBLK / 8) + (bid >> 3);   // 768%8==0 -> bijective
    const int otile = swz >> 7;      // 0..5
    const int mtile = swz & 127;     // 0..127
    const int m0 = mtile * BM, o0 = otile * BO;

    const int lane = tid & 63, wc = tid >> 6;       // 4 o-waves
    const int lrow = lane & 15, quad = lane >> 4;
    const int nbase = m0 & (NN - 1);

    // per-row-block bases: x rows (4 ptrs), coef via one ptr + imm offsets
    const float* xb[4];
#pragma unroll
    for (int im = 0; im < 4; ++im) xb[im] = x + (long)(m0 + im * 16 + lrow) * CC;
    const float* cptr = coef + (long)(nbase + lrow) * RR;   // + im*256 + r floats

    f32x4 acc[4][2] = {};

    // stage B-tile at k-offset koff into buffer b (async DMA, global-side XOR swizzle)
    auto STAGE = [&](int b, int koff) {
#pragma unroll
        for (int s = 0; s < 4; ++s) {
            int u = s * 256 + tid;             // 1024 chunks of 16B
            int row = u >> 3, cl = u & 7;
            int g = cl ^ (row & 7);
            const __bf16* gp = wbf + (long)(o0 + row) * KK + koff + g * 8;
            gl_lds16(gp, ((char*)lB[b]) + u * 16);
        }
    };

    STAGE(0, 0);                                   // tile (cw=0, r=0)
    f32x2 xw[4][8];                                // lane's 16 x per row-block
#pragma unroll
    for (int im = 0; im < 4; ++im) {
        float4 a  = *(const float4*)(xb[im] + quad * 8);
        float4 b4 = *(const float4*)(xb[im] + quad * 8 + 4);
        float4 c4 = *(const float4*)(xb[im] + 32 + quad * 8);
        float4 d4 = *(const float4*)(xb[im] + 32 + quad * 8 + 4);
        xw[im][0] = mk2(a.x, a.y);  xw[im][1] = mk2(a.z, a.w);
        xw[im][2] = mk2(b4.x, b4.y); xw[im][3] = mk2(b4.z, b4.w);
        xw[im][4] = mk2(c4.x, c4.y); xw[im][5] = mk2(c4.z, c4.w);
        xw[im][6] = mk2(d4.x, d4.y); xw[im][7] = mk2(d4.z, d4.w);
    }
    __syncthreads();

#pragma unroll 1
    for (int cw = 0; cw < CW; ++cw) {
        if (cw) {                                  // refresh x window (16 loads / 16 tiles)
#pragma unroll
            for (int im = 0; im < 4; ++im) {
                float4 a  = *(const float4*)(xb[im] + cw * 64 + quad * 8);
                float4 b4 = *(const float4*)(xb[im] + cw * 64 + quad * 8 + 4);
                float4 c4 = *(const float4*)(xb[im] + cw * 64 + 32 + quad * 8);
                float4 d4 = *(const float4*)(xb[im] + cw * 64 + 32 + quad * 8 + 4);
                xw[im][0] = mk2(a.x, a.y);  xw[im][1] = mk2(a.z, a.w);
                xw[im][2] = mk2(b4.x, b4.y); xw[im][3] = mk2(b4.z, b4.w);
                xw[im][4] = mk2(c4.x, c4.y); xw[im][5] = mk2(c4.z, c4.w);
                xw[im][6] = mk2(d4.x, d4.y); xw[im][7] = mk2(d4.z, d4.w);
            }
        }
#pragma unroll
        for (int r = 0; r < RR; ++r) {             // fully unrolled: static reg indices
            const int cur = r & 1;
            if (!(cw == CW - 1 && r == RR - 1)) {
                // next tile in the MONOTONIC walk: +64 elems (128B)
                int koff = cw * 1024 + r * 64 + 64;
                STAGE(cur ^ 1, koff);              // drains at end-of-tile barrier
            }
            float cf[4];
#pragma unroll
            for (int im = 0; im < 4; ++im) cf[im] = cptr[im * 256 + r];  // imm offsets, L1
#pragma unroll
            for (int ks = 0; ks < 2; ++ks) {
                const int kb = ks * 4 + quad;
                bf16x8 bfr[2];
#pragma unroll
                for (int io = 0; io < 2; ++io) {
                    int brow = wc * 32 + io * 16 + lrow;
                    bfr[io] = *(const bf16x8*)(&lB[cur][brow * BK + ((kb ^ (brow & 7))) * 8]);
                }
#pragma unroll
                for (int im = 0; im < 4; ++im) {
                    const f32x2 c2 = mk2(cf[im], cf[im]);
                    bf16x8 af;
#pragma unroll
                    for (int h = 0; h < 4; ++h) {
                        f32x2 pr = xw[im][ks * 4 + h] * c2;   // v_pk_mul_f32
                        af[2 * h]     = (__bf16)pr[0];
                        af[2 * h + 1] = (__bf16)pr[1];
                    }
                    acc[im][0] = __builtin_amdgcn_mfma_f32_16x16x32_bf16(
                        af, bfr[0], acc[im][0], 0, 0, 0);
                    acc[im][1] = __builtin_amdgcn_mfma_f32_16x16x32_bf16(
                        af, bfr[1], acc[im][1], 0, 0, 0);
                }
            }
            __syncthreads();   // single barrier/k-tile: drains DMA, guards buffers
        }
    }

    // ---- epilogue: D col=lane&15 (o), row=quad*4+reg (m); add bias_term ----
#pragma unroll
    for (int im = 0; im < 4; ++im) {
#pragma unroll
        for (int io = 0; io < 2; ++io) {
            int o = o0 + wc * 32 + io * 16 + lrow;
#pragma unroll
            for (int rr2 = 0; rr2 < 4; ++rr2) {
                int moff = im * 16 + quad * 4 + rr2;
                long m = m0 + moff;
                out[m * OO + o] = acc[im][io][rr2] + bterm[(long)(nbase + moff) * OO + o];
            }
        }
    }
}

// ---- fallback if workspace too small (correctness-only) ----
__global__ void k_naive(const float* __restrict__ x, const float* __restrict__ coef,
                        const float* __restrict__ w, const float* __restrict__ bias,
                        float* __restrict__ out) {
    long i = (long)blockIdx.x * 256 + threadIdx.x;
    if (i >= (long)MM * OO) return;
    int o = (int)(i % OO);
    long m = i / OO;
    int n = (int)(m & (NN - 1));
    float cf[16];
#pragma unroll
    for (int r = 0; r < 16; ++r) cf[r] = coef[n * RR + r];
    const float* xr = x + m * CC;
    const float* wr = w + (long)o * CC * RR;
    float s = 0.f;
    for (int c = 0; c < CC; ++c) {
        float t = 0.f;
#pragma unroll
        for (int r = 0; r < 16; ++r) t += cf[r] * wr[c * RR + r];
        s += xr[c] * t;
    }
    float bs = 0.f;
#pragma unroll
    for (int r = 0; r < 16; ++r) bs += cf[r] * bias[o * RR + r];
    out[i] = s + bs;
}

extern "C" void kernel_launch(void* const* d_in, const int* in_sizes, int n_in,
                              void* d_out, int out_size, void* d_ws, size_t ws_size,
                              hipStream_t stream) {
    const float* x    = (const float*)d_in[0];
    const float* coef = (const float*)d_in[1];
    const float* w    = (const float*)d_in[2];
    const float* bias = (const float*)d_in[3];
    float* out = (float*)d_out;

    const size_t wbf_bytes = (size_t)OO * KK * sizeof(__bf16);   // 18,874,368
    const size_t bt_bytes  = (size_t)NN * OO * sizeof(float);    //  3,145,728

    if (ws_size >= wbf_bytes + bt_bytes) {
        __bf16* wbf  = (__bf16*)d_ws;
        float*  btrm = (float*)((char*)d_ws + wbf_bytes);
        k_prep<<<7680, 256, 0, stream>>>(w, coef, bias, wbf, btrm);
        k_gemm<<<NBLK, NTHR, 0, stream>>>(x, coef, wbf, btrm, out);
    } else {
        k_naive<<<(int)(((long)MM * OO + 255) / 256), 256, 0, stream>>>(x, coef, w, bias, out);
    }
}